// Round 9
// baseline (372.647 us; speedup 1.0000x reference)
//
#include <hip/hip_runtime.h>
#include <hip/hip_bf16.h>

typedef __attribute__((ext_vector_type(8))) short s8v;   // 8 x bf16 (as shorts)
typedef __attribute__((ext_vector_type(4))) short s4v;   // 4 x bf16
typedef __attribute__((ext_vector_type(4))) float f4v;   // MFMA C/D frag

__device__ __forceinline__ short f2bf(float f){
  unsigned u = __builtin_bit_cast(unsigned, f);
  u += 0x7fffu + ((u >> 16) & 1u);          // round-to-nearest-even
  return (short)(u >> 16);
}

__device__ __forceinline__ f4v mfma16(s8v a, s8v b, f4v c){
  return __builtin_amdgcn_mfma_f32_16x16x32_bf16(a, b, c, 0, 0, 0);
}

// LDS-only barrier: waits LDS ops but lets global stores/loads stay in flight
// (avoids the vmcnt(0) drain __syncthreads would force — guide §5 m97).
__device__ __forceinline__ void ldsbar(){
  asm volatile("s_waitcnt lgkmcnt(0)" ::: "memory");
  __builtin_amdgcn_s_barrier();
  __builtin_amdgcn_sched_barrier(0);
}

#define LOG2E 1.44269504088896f

// ---------------- K0: weight transpose/cast ---------------------------------
// Wt[w][n][k] = bf16(W[k][n]);  w: 0=Wq 1=Wk 2=Wv 3=Wfc
__global__ __launch_bounds__(256) void prep_kernel(
    const float* __restrict__ Wq, const float* __restrict__ Wk,
    const float* __restrict__ Wv, const float* __restrict__ Wfc,
    short* __restrict__ Wt)
{
  const int w = blockIdx.x >> 10;
  const float* __restrict__ W = (w==0)?Wq:(w==1)?Wk:(w==2)?Wv:Wfc;
  const int idx = (blockIdx.x & 1023)*256 + threadIdx.x; // 0..262143
  const int kk = idx >> 9, n = idx & 511;
  Wt[w*262144 + n*512 + kk] = f2bf(W[idx]);
}

// ---------------- K1: QKV projection GEMM (128x128 tiles) + mask tail -------
// blocks [0,1536): GEMM with XCD-chunked swizzle; 4 waves of 64x64 output,
// 16 MFMAs per k-step per wave. Double-buffered LDS A staging (1 ldsbar per
// k-step) + register prefetch. V epilogue transposes through LDS (unioned
// with A buffers) for coalesced Vt writes.
// blocks [1536,3584): mask->bits (overlaps GEMM compute).
__global__ __launch_bounds__(256) void proj_kernel(
    const float* __restrict__ qin, const float* __restrict__ kin,
    const float* __restrict__ vin, const short* __restrict__ Wt,
    const int* __restrict__ mask, unsigned* __restrict__ bits,
    short* __restrict__ Qh, short* __restrict__ Kh, short* __restrict__ Vt)
{
  if (blockIdx.x >= 1536){
    const int lane = threadIdx.x & 63;
    const int wid = (blockIdx.x - 1536)*4 + (threadIdx.x >> 6);
    for (int i = 0; i < 32; ++i){
      const int c = wid*32 + i;                     // 64-int chunk index
      int mv = __builtin_nontemporal_load(&mask[(size_t)c*64 + lane]);
      unsigned long long bal = __ballot(mv != 0);
      if (lane == 0)  bits[c*2]   = (unsigned)bal;
      if (lane == 32) bits[c*2+1] = (unsigned)(bal >> 32);
    }
    return;
  }
  const int work = (blockIdx.x & 7)*192 + (blockIdx.x >> 3);   // 1536%8==0
  const int z = work / 512;                        // 0=Q 1=K 2=V
  const int r = work - z*512;
  const int mt = r >> 2, nt = r & 3;
  const float* __restrict__ A = (z==0) ? qin : (z==1) ? kin : vin;
  const short* __restrict__ W = Wt + z*262144;
  const int m0 = mt*128, n0 = nt*128;
  // union: A dbuf (2 x 128x40 shorts = 20480 B) vs V-transpose (128x136x2 = 34816 B)
  __shared__ __align__(16) char smem[34816];
  short* Alds = (short*)smem;                      // [2][128*40]
  short* Tlds = (short*)smem;                      // [128][136]
  const int tid = threadIdx.x, lane = tid & 63, wave = tid >> 6;
  const int wm = wave >> 1, wn = wave & 1;         // 2x2 wave grid of 64x64
  const int col = lane & 15, kg = lane >> 4;

  f4v acc[4][4];
  #pragma unroll
  for (int i=0;i<4;i++)
    #pragma unroll
    for (int j=0;j<4;j++) acc[i][j] = (f4v){0.f,0.f,0.f,0.f};

  const int arow = tid >> 1, aoff = (tid & 1)*16;  // 2 threads per row, 16 f32 each
  const float* Ap = A + (size_t)(m0 + arow)*512 + aoff;

  float4 x0 = *(const float4*)(Ap);
  float4 x1 = *(const float4*)(Ap + 4);
  float4 x2 = *(const float4*)(Ap + 8);
  float4 x3 = *(const float4*)(Ap + 12);
  int buf = 0;

  for (int k0 = 0; k0 < 512; k0 += 32){
    s8v ab0, ab1;
    ab0[0]=f2bf(x0.x); ab0[1]=f2bf(x0.y); ab0[2]=f2bf(x0.z); ab0[3]=f2bf(x0.w);
    ab0[4]=f2bf(x1.x); ab0[5]=f2bf(x1.y); ab0[6]=f2bf(x1.z); ab0[7]=f2bf(x1.w);
    ab1[0]=f2bf(x2.x); ab1[1]=f2bf(x2.y); ab1[2]=f2bf(x2.z); ab1[3]=f2bf(x2.w);
    ab1[4]=f2bf(x3.x); ab1[5]=f2bf(x3.y); ab1[6]=f2bf(x3.z); ab1[7]=f2bf(x3.w);
    short* Aw = Alds + buf*5120 + arow*40 + aoff;
    *(s8v*)Aw = ab0;
    *(s8v*)(Aw + 8) = ab1;
    if (k0 < 480){                  // prefetch next A tile (floats past barrier)
      x0 = *(const float4*)(Ap + k0 + 32);
      x1 = *(const float4*)(Ap + k0 + 36);
      x2 = *(const float4*)(Ap + k0 + 40);
      x3 = *(const float4*)(Ap + k0 + 44);
    }
    ldsbar();                       // write visible; WAR covered by next barrier
    s8v af[4];
    #pragma unroll
    for (int fr=0; fr<4; fr++)
      af[fr] = *(const s8v*)(Alds + buf*5120 + (wm*64 + fr*16 + col)*40 + kg*8);
    #pragma unroll
    for (int f=0; f<4; f++){
      const int n = n0 + wn*64 + f*16 + col;
      s8v bf = *(const s8v*)(W + n*512 + k0 + kg*8);
      #pragma unroll
      for (int fr=0; fr<4; fr++)
        acc[fr][f] = mfma16(af[fr], bf, acc[fr][f]);
    }
    buf ^= 1;
  }

  if (z < 2){
    const float scale = (z==0) ? 0.125f*LOG2E : 1.0f;
    short* D = (z==0) ? Qh : Kh;
    #pragma unroll
    for (int fr=0; fr<4; fr++)
      #pragma unroll
      for (int f=0; f<4; f++)
        #pragma unroll
        for (int j=0; j<4; j++){
          int rr = m0 + wm*64 + fr*16 + kg*4 + j; // global row = b*1024 + l
          int c = n0 + wn*64 + f*16 + col;        // 0..511 -> (h,d)
          int b = rr >> 10, l = rr & 1023, hh = c >> 6, d = c & 63;
          D[((size_t)(b*8+hh)*1024 + l)*64 + d] = f2bf(acc[fr][f][j] * scale);
        }
  } else {
    ldsbar();                       // all waves done with Alds before reuse
    // stage transposed tile: Tlds[c_local][r_local], row stride 136
    #pragma unroll
    for (int fr=0; fr<4; fr++)
      #pragma unroll
      for (int f=0; f<4; f++)
        #pragma unroll
        for (int j=0; j<4; j++){
          const int rl = wm*64 + fr*16 + kg*4 + j;
          const int cl = wn*64 + f*16 + col;
          Tlds[cl*136 + rl] = f2bf(acc[fr][f][j]);
        }
    ldsbar();
    // coalesced Vt writes: 16 lanes cover 256B contiguous per (h,d) column
    const int b = m0 >> 10, lbase = m0 & 1023;
    #pragma unroll
    for (int it=0; it<8; ++it){
      const int idx = it*256 + tid;               // 0..2047
      const int cl = idx >> 4, rc = idx & 15;
      const int c = n0 + cl, hh = c >> 6, d = c & 63;
      s8v vv = *(const s8v*)(Tlds + cl*136 + rc*8);
      *(s8v*)(Vt + ((size_t)(b*8+hh)*64 + d)*1024 + lbase + rc*8) = vv;
    }
  }
}

// ---------------- K2: attention, recompute-QK^T two-pass, QBLK=64 -----------
// swapped MFMA: mfma(K,Q) -> lane holds 4 consecutive k for one q-row.
// Pass A (col-split): QK^T -> exp2 -> masked UNNORMALIZED P: row sums + PV
// through xor-swizzled LDS Pb (lgkmcnt-only barriers). ctx = cacc * rowinv.
// Pass B (streaming, ZERO barriers, zero LDS): recompute scores, NT-write
// normalized attn; stores pipeline freely, never drained.
__global__ __launch_bounds__(256) void attn_kernel(
  const short* __restrict__ Qh, const short* __restrict__ Kh,
  const short* __restrict__ Vt, const unsigned* __restrict__ bits,
  float* __restrict__ attn, short* __restrict__ ctx)
{
  const int work = ((blockIdx.x & 7) << 8) | (blockIdx.x >> 3);  // 2048%8==0
  const int bh = work >> 4;
  const int q0 = (work & 15) * 64;
  const int b = bh >> 3, h = bh & 7;
  __shared__ unsigned mb[64*33];                  // mask bits, stride 33 words
  __shared__ __align__(16) short Pb[64*128];      // P tile, xor-swizzled
  __shared__ float red[256];
  __shared__ float rowinv[64];
  const int tid = threadIdx.x, lane = tid & 63, wave = tid >> 6;
  const int col = lane & 15, kg = lane >> 4;
  const short* Qb = Qh + (size_t)bh*65536;
  const short* Kb = Kh + (size_t)bh*65536;
  const short* Vb = Vt + (size_t)bh*65536;
  const f4v zf = (f4v){0.f,0.f,0.f,0.f};

  { // stage this block's mask bits (64 rows x 32 words) into LDS
    const int r = tid >> 2, w = (tid & 3)*8;
    const unsigned* src = bits + (size_t)(b*1024 + q0 + r)*32 + w;
    uint4 w0 = *(const uint4*)src;
    uint4 w1 = *(const uint4*)(src + 4);
    unsigned* dst = &mb[r*33 + w];
    dst[0]=w0.x; dst[1]=w0.y; dst[2]=w0.z; dst[3]=w0.w;
    dst[4]=w1.x; dst[5]=w1.y; dst[6]=w1.z; dst[7]=w1.w;
  }

  // Q fragments (B-operand): rows q0..q0+63
  s8v qf[4][2];
  #pragma unroll
  for (int qi = 0; qi < 4; ++qi)
    #pragma unroll
    for (int ks = 0; ks < 2; ++ks)
      qf[qi][ks] = *(const s8v*)(Qb + (q0 + qi*16 + col)*64 + ks*32 + kg*8);

  __syncthreads();

  // ---- pass A: scores -> masked unnormalized P -> row sums + PV ----
  float sum[4] = {0.f, 0.f, 0.f, 0.f};
  f4v cacc[4] = {zf, zf, zf, zf};
  const int d0 = wave*16;
  const int sw = (col & 7) << 3;                  // Pb swizzle (shorts)
  for (int it = 0; it < 8; ++it){
    const int c0 = it*128 + wave*32;
    unsigned mw[4];
    #pragma unroll
    for (int qi = 0; qi < 4; ++qi) mw[qi] = mb[(qi*16 + col)*33 + (c0>>5)];
    #pragma unroll
    for (int ch = 0; ch < 2; ++ch){
      const int cc = c0 + ch*16;
      const short* kp = Kb + (cc + col)*64 + kg*8;
      s8v kf0 = *(const s8v*)kp;
      s8v kf1 = *(const s8v*)(kp + 32);
      #pragma unroll
      for (int qi = 0; qi < 4; ++qi){
        f4v a = mfma16(kf0, qf[qi][0], zf);
        a = mfma16(kf1, qf[qi][1], a);
        s4v pk;
        #pragma unroll
        for (int j = 0; j < 4; ++j){
          const int bit = ch*16 + kg*4 + j;
          float e = exp2f(a[j]);
          float p = ((mw[qi]>>bit)&1) ? 0.f : e;
          sum[qi] += p;
          pk[j] = f2bf(p);
        }
        // stage UNNORMALIZED P (bf16) for PV
        *(s4v*)&Pb[(qi*16 + col)*128 + ((wave*32 + ch*16 + kg*4) ^ sw)] = pk;
      }
    }
    ldsbar();                     // Pb writes visible (LDS-only wait)
    #pragma unroll
    for (int sub = 0; sub < 4; ++sub){
      s8v vf = *(const s8v*)(Vb + (size_t)(d0 + col)*1024 + it*128 + sub*32 + kg*8);
      const int kr = (sub*32 + kg*8) ^ sw;
      #pragma unroll
      for (int qi = 0; qi < 4; ++qi){
        s8v pa = *(const s8v*)&Pb[(qi*16 + col)*128 + kr];
        cacc[qi] = mfma16(pa, vf, cacc[qi]);
      }
    }
    ldsbar();                     // all waves' Pb reads done before next write
  }

  // reduce row sums -> rowinv
  #pragma unroll
  for (int qi = 0; qi < 4; ++qi){
    sum[qi] += __shfl_xor(sum[qi], 16);
    sum[qi] += __shfl_xor(sum[qi], 32);
  }
  if (kg == 0){
    #pragma unroll
    for (int qi = 0; qi < 4; ++qi) red[wave*64 + qi*16 + col] = sum[qi];
  }
  __syncthreads();
  if (tid < 64)
    rowinv[tid] = 1.0f / (red[tid] + red[64+tid] + red[128+tid] + red[192+tid]);
  __syncthreads();

  // ctx epilogue: normalize the unnormalized PV accumulator
  short* cb = ctx + (size_t)(b*1024 + q0)*512 + h*64 + d0 + col;
  #pragma unroll
  for (int qi = 0; qi < 4; ++qi)
    #pragma unroll
    for (int j = 0; j < 4; ++j)
      cb[(size_t)(qi*16 + kg*4 + j)*512] =
          f2bf(cacc[qi][j] * rowinv[qi*16 + kg*4 + j]);

  // ---- pass B: pure streaming normalized attn writes (no barriers/LDS) ----
  float inv[4];
  #pragma unroll
  for (int qi = 0; qi < 4; ++qi) inv[qi] = rowinv[qi*16 + col];
  float* ab = attn + (size_t)(bh*1024 + q0)*1024;
  for (int it = 0; it < 8; ++it){
    const int c0 = it*128 + wave*32;
    unsigned mw[4];
    #pragma unroll
    for (int qi = 0; qi < 4; ++qi) mw[qi] = mb[(qi*16 + col)*33 + (c0>>5)];
    #pragma unroll
    for (int ch = 0; ch < 2; ++ch){
      const int cc = c0 + ch*16;
      const short* kp = Kb + (cc + col)*64 + kg*8;
      s8v kf0 = *(const s8v*)kp;
      s8v kf1 = *(const s8v*)(kp + 32);
      #pragma unroll
      for (int qi = 0; qi < 4; ++qi){
        f4v a = mfma16(kf0, qf[qi][0], zf);
        a = mfma16(kf1, qf[qi][1], a);
        f4v p;
        #pragma unroll
        for (int j = 0; j < 4; ++j){
          const int bit = ch*16 + kg*4 + j;
          float e = exp2f(a[j]) * inv[qi];
          p[j] = ((mw[qi]>>bit)&1) ? 0.f : e;
        }
        __builtin_nontemporal_store(p,
            (f4v*)(ab + (size_t)(qi*16 + col)*1024 + cc + kg*4));
      }
    }
  }
}

// ---------------- K3: out-proj GEMM + residual + fused LayerNorm ------------
// 32 rows x 512 cols per block (full N -> LN block-local). grid 512. 4 waves,
// each wave owns a 128-col slice: acc[2 mfrag][8 nfrag]. Double-buffered LDS
// (1 ldsbar per k-step) + register prefetch.
__global__ __launch_bounds__(256) void outproj_ln_kernel(
  const short* __restrict__ ctx, const short* __restrict__ Wf,
  const float* __restrict__ resid, const float* __restrict__ gamma,
  const float* __restrict__ beta, float* __restrict__ out)
{
  const int m0 = blockIdx.x * 32;
  __shared__ __align__(16) short Alds[2][32*40];
  __shared__ float sred[32*4], qred[32*4];
  __shared__ float mLds[32], rLds[32];
  const int tid = threadIdx.x, lane = tid & 63, wave = tid >> 6;
  const int col = lane & 15, kg = lane >> 4;
  const int n0 = wave * 128;

  f4v acc[2][8];
  #pragma unroll
  for (int mf=0; mf<2; mf++)
    #pragma unroll
    for (int nf=0; nf<8; nf++) acc[mf][nf] = (f4v){0.f,0.f,0.f,0.f};

  const int arow = tid >> 3, ac = (tid & 7)*4;
  const short* Ap = ctx + (size_t)(m0 + arow)*512 + ac;

  s4v av = *(const s4v*)(Ap);
  int buf = 0;

  for (int k0 = 0; k0 < 512; k0 += 32){
    *(s4v*)&Alds[buf][arow*40 + ac] = av;
    if (k0 < 480) av = *(const s4v*)(Ap + k0 + 32);   // prefetch next
    ldsbar();                       // write visible; WAR covered by next barrier
    s8v af[2];
    #pragma unroll
    for (int mf=0; mf<2; mf++)
      af[mf] = *(const s8v*)&Alds[buf][(mf*16 + col)*40 + kg*8];
    #pragma unroll
    for (int nf=0; nf<8; nf++){
      s8v bf = *(const s8v*)(Wf + (size_t)(n0 + nf*16 + col)*512 + k0 + kg*8);
      #pragma unroll
      for (int mf=0; mf<2; mf++)
        acc[mf][nf] = mfma16(af[mf], bf, acc[mf][nf]);
    }
    buf ^= 1;
  }

  float g[8], bt[8];
  #pragma unroll
  for (int nf=0; nf<8; nf++){
    g[nf]  = gamma[n0 + nf*16 + col];
    bt[nf] = beta[n0 + nf*16 + col];
  }

  // residual add (in place) + per-row partial stats -> LDS reduce
  #pragma unroll
  for (int mf=0; mf<2; mf++)
    #pragma unroll
    for (int j=0; j<4; j++){
      const int rl = mf*16 + kg*4 + j;
      const size_t r = (size_t)(m0 + rl);
      float s = 0.f, qq = 0.f;
      #pragma unroll
      for (int nf=0; nf<8; nf++){
        float y = acc[mf][nf][j] + resid[r*512 + n0 + nf*16 + col];
        acc[mf][nf][j] = y;
        s += y; qq += y*y;
      }
      #pragma unroll
      for (int d=1; d<16; d<<=1){ s += __shfl_xor(s, d); qq += __shfl_xor(qq, d); }
      if (col == 0){ sred[rl*4 + wave] = s; qred[rl*4 + wave] = qq; }
    }
  __syncthreads();
  if (tid < 32){
    float S = sred[tid*4] + sred[tid*4+1] + sred[tid*4+2] + sred[tid*4+3];
    float Q = qred[tid*4] + qred[tid*4+1] + qred[tid*4+2] + qred[tid*4+3];
    float mean = S * (1.0f/512.0f);
    float var  = Q * (1.0f/512.0f) - mean*mean;
    mLds[tid] = mean;
    rLds[tid] = rsqrtf(var + 1e-6f);
  }
  __syncthreads();

  #pragma unroll
  for (int mf=0; mf<2; mf++)
    #pragma unroll
    for (int j=0; j<4; j++){
      const int rl = mf*16 + kg*4 + j;
      const size_t r = (size_t)(m0 + rl);
      const float mean = mLds[rl], rs = rLds[rl];
      #pragma unroll
      for (int nf=0; nf<8; nf++)
        out[r*512 + n0 + nf*16 + col] = (acc[mf][nf][j] - mean)*rs*g[nf] + bt[nf];
    }
}

extern "C" void kernel_launch(void* const* d_in, const int* in_sizes, int n_in,
                              void* d_out, int out_size, void* d_ws, size_t ws_size,
                              hipStream_t stream) {
  const float* q    = (const float*)d_in[0];
  const float* k    = (const float*)d_in[1];
  const float* v    = (const float*)d_in[2];
  const int*   mask = (const int*)d_in[3];
  const float* Wq   = (const float*)d_in[4];
  const float* Wk   = (const float*)d_in[5];
  const float* Wv   = (const float*)d_in[6];
  const float* Wfc  = (const float*)d_in[7];
  const float* gamma= (const float*)d_in[8];
  const float* beta = (const float*)d_in[9];

  char* ws = (char*)d_ws;
  short* Wt  = (short*)(ws);                       // 4*512*512 bf16 = 2 MB
  short* Qh  = (short*)(ws + ((size_t)2<<20));     // 16 MB
  short* Kh  = (short*)(ws + ((size_t)18<<20));    // 16 MB
  short* Vt  = (short*)(ws + ((size_t)34<<20));    // 16 MB
  short* ctx = (short*)(ws + ((size_t)50<<20));    // 16 MB

  float* out  = (float*)d_out;                     // [16384][512]
  float* attn = out + (size_t)16384*512;           // [128][1024][1024]
  // mask bitmask lives in d_out's `out` region (2 MB); written by proj tail,
  // consumed by attn_kernel, overwritten by outproj_ln (stream-ordered, safe).
  unsigned* bits = (unsigned*)d_out;

  prep_kernel<<<dim3(4096,1,1), 256, 0, stream>>>(Wq, Wk, Wv, Wfc, Wt);
  proj_kernel <<<dim3(3584,1,1), 256, 0, stream>>>(q, k, v, Wt, mask, bits,
                                                   Qh, Kh, Vt);
  attn_kernel <<<dim3(2048,1,1), 256, 0, stream>>>(Qh, Kh, Vt, bits, attn, ctx);
  outproj_ln_kernel<<<dim3(512,1,1), 256, 0, stream>>>(ctx, Wt + 3*262144, q,
                                                       gamma, beta, out);
}

// Round 10
// 332.735 us; speedup vs baseline: 1.1200x; 1.1200x over previous
//
#include <hip/hip_runtime.h>
#include <hip/hip_bf16.h>

typedef __attribute__((ext_vector_type(8))) short s8v;   // 8 x bf16 (as shorts)
typedef __attribute__((ext_vector_type(4))) short s4v;   // 4 x bf16
typedef __attribute__((ext_vector_type(4))) float f4v;   // MFMA C/D frag

__device__ __forceinline__ short f2bf(float f){
  unsigned u = __builtin_bit_cast(unsigned, f);
  u += 0x7fffu + ((u >> 16) & 1u);          // round-to-nearest-even
  return (short)(u >> 16);
}

__device__ __forceinline__ f4v mfma16(s8v a, s8v b, f4v c){
  return __builtin_amdgcn_mfma_f32_16x16x32_bf16(a, b, c, 0, 0, 0);
}

// LDS-only barrier: waits LDS ops but lets global stores/loads stay in flight
// (avoids the vmcnt(0) drain __syncthreads would force — guide §5 m97).
__device__ __forceinline__ void ldsbar(){
  asm volatile("s_waitcnt lgkmcnt(0)" ::: "memory");
  __builtin_amdgcn_s_barrier();
  __builtin_amdgcn_sched_barrier(0);
}

#define LOG2E 1.44269504088896f

// ---------------- K0: fused prep: mask->bits  +  tiled weight transpose -----
// blocks [0,2048): bitmask (1 = masked).
// blocks [2048,2304): Wt[w][n][k]=bf16(W[k][n]) via 64x64 LDS tiles
// (coalesced reads AND 32B/lane contiguous writes — the old per-element
// version scattered 2B writes at 1KB stride).
__global__ __launch_bounds__(256) void prep_kernel(
    const int* __restrict__ mask, unsigned* __restrict__ bits,
    const float* __restrict__ Wq, const float* __restrict__ Wk,
    const float* __restrict__ Wv, const float* __restrict__ Wfc,
    short* __restrict__ Wt)
{
  __shared__ float tile[64][65];
  if (blockIdx.x < 2048){
    const int lane = threadIdx.x & 63;
    const int wid = blockIdx.x*4 + (threadIdx.x >> 6);
    for (int i = 0; i < 32; ++i){
      const int c = wid*32 + i;                     // 64-int chunk index
      int mv = __builtin_nontemporal_load(&mask[(size_t)c*64 + lane]);
      unsigned long long bal = __ballot(mv != 0);
      if (lane == 0)  bits[c*2]   = (unsigned)bal;
      if (lane == 32) bits[c*2+1] = (unsigned)(bal >> 32);
    }
  } else {
    const int bid = blockIdx.x - 2048;
    const int w = bid >> 6;                         // matrix
    const int tr = (bid & 63) >> 3, tc = bid & 7;   // 64x64 tile coords
    const int kr0 = tr*64, nc0 = tc*64;
    const float* __restrict__ W = (w==0)?Wq:(w==1)?Wk:(w==2)?Wv:Wfc;
    const int tid = threadIdx.x;
    const int rr = tid >> 6, cc = tid & 63;
    #pragma unroll
    for (int i = 0; i < 16; ++i)
      tile[rr + i*4][cc] = W[(size_t)(kr0 + rr + i*4)*512 + nc0 + cc];
    __syncthreads();
    const int nl = tid >> 2, kc = tid & 3;          // out row n, 16-k chunk
    short* dst = Wt + w*262144 + (size_t)(nc0 + nl)*512 + kr0 + kc*16;
    #pragma unroll
    for (int h = 0; h < 2; ++h){
      s8v o;
      #pragma unroll
      for (int j = 0; j < 8; ++j) o[j] = f2bf(tile[kc*16 + h*8 + j][nl]);
      *(s8v*)(dst + h*8) = o;
    }
  }
}

// ---------------- K1: QKV projection GEMM -----------------------------------
// Double-buffered LDS A staging (1 ldsbar per k-step) + register prefetch.
// Q scale folds 1/sqrt(64) AND log2e (attn uses bare v_exp_f32 = 2^x).
__global__ __launch_bounds__(256) void proj_kernel(
    const float* __restrict__ qin, const float* __restrict__ kin,
    const float* __restrict__ vin, const short* __restrict__ Wt,
    short* __restrict__ Qh, short* __restrict__ Kh, short* __restrict__ Vt)
{
  const int work = (blockIdx.x & 7)*384 + (blockIdx.x >> 3);   // 3072%8==0
  const int z = work >> 10;                       // 0=Q 1=K 2=V
  const int r = work & 1023;
  const int mt = r >> 2, nt = r & 3;
  const float* __restrict__ A = (z==0) ? qin : (z==1) ? kin : vin;
  const short* __restrict__ W = Wt + z*262144;
  const int m0 = mt*64, n0 = nt*128;
  __shared__ __align__(16) short Alds[2][64*40];  // dbuf, padded stride 40
  __shared__ __align__(16) short Tlds[128*68];    // V-transpose staging
  const int tid = threadIdx.x, lane = tid & 63, wave = tid >> 6;
  const int wm = wave >> 1, wn = wave & 1;        // 2x2 wave grid
  const int col = lane & 15, kg = lane >> 4;
  f4v acc[2][4];
  #pragma unroll
  for (int i=0;i<2;i++)
    #pragma unroll
    for (int j=0;j<4;j++) acc[i][j] = (f4v){0.f,0.f,0.f,0.f};

  const int arow = tid >> 2, aoff = (tid & 3)*8;
  const float* Ap = A + (size_t)(m0 + arow)*512 + aoff;

  float4 x0 = *(const float4*)(Ap);
  float4 x1 = *(const float4*)(Ap + 4);
  int buf = 0;

  for (int k0 = 0; k0 < 512; k0 += 32){
    s8v ab;
    ab[0]=f2bf(x0.x); ab[1]=f2bf(x0.y); ab[2]=f2bf(x0.z); ab[3]=f2bf(x0.w);
    ab[4]=f2bf(x1.x); ab[5]=f2bf(x1.y); ab[6]=f2bf(x1.z); ab[7]=f2bf(x1.w);
    *(s8v*)&Alds[buf][arow*40 + aoff] = ab;
    if (k0 < 480){                  // prefetch next A tile (floats past barrier)
      x0 = *(const float4*)(Ap + k0 + 32);
      x1 = *(const float4*)(Ap + k0 + 36);
    }
    ldsbar();                       // write visible; WAR on buf^1 covered by
                                    // the NEXT iteration's barrier (dbuf)
    s8v af0 = *(const s8v*)&Alds[buf][(wm*32 + col)*40 + kg*8];
    s8v af1 = *(const s8v*)&Alds[buf][(wm*32 + 16 + col)*40 + kg*8];
    #pragma unroll
    for (int f=0; f<4; f++){
      const int n = n0 + wn*64 + f*16 + col;
      s8v bf = *(const s8v*)(W + n*512 + k0 + kg*8);
      acc[0][f] = mfma16(af0, bf, acc[0][f]);
      acc[1][f] = mfma16(af1, bf, acc[1][f]);
    }
    buf ^= 1;
  }

  if (z < 2){
    const float scale = (z==0) ? 0.125f*LOG2E : 1.0f;
    short* D = (z==0) ? Qh : Kh;
    #pragma unroll
    for (int fr=0; fr<2; fr++)
      #pragma unroll
      for (int f=0; f<4; f++)
        #pragma unroll
        for (int j=0; j<4; j++){
          int rr = m0 + wm*32 + fr*16 + kg*4 + j; // global row = b*1024 + l
          int c = n0 + wn*64 + f*16 + col;        // 0..511 -> (h,d)
          int b = rr >> 10, l = rr & 1023, hh = c >> 6, d = c & 63;
          D[((size_t)(b*8+hh)*1024 + l)*64 + d] = f2bf(acc[fr][f][j] * scale);
        }
  } else {
    // stage transposed tile: Tlds[c_local][r_local], pad rows 64->68
    #pragma unroll
    for (int fr=0; fr<2; fr++)
      #pragma unroll
      for (int f=0; f<4; f++)
        #pragma unroll
        for (int j=0; j<4; j++){
          const int rl = wm*32 + fr*16 + kg*4 + j;
          const int cl = wn*64 + f*16 + col;
          Tlds[cl*68 + rl] = f2bf(acc[fr][f][j]);
        }
    ldsbar();
    // coalesced Vt writes: 16B per lane along l
    const int b = m0 >> 10, lbase = m0 & 1023;
    #pragma unroll
    for (int it=0; it<4; ++it){
      const int idx = it*256 + tid;               // 0..1023
      const int cl = idx >> 3, rc = idx & 7;
      const int c = n0 + cl, hh = c >> 6, d = c & 63;
      s8v vv = *(const s8v*)&Tlds[cl*68 + rc*8];
      *(s8v*)(Vt + ((size_t)(b*8+hh)*64 + d)*1024 + lbase + rc*8) = vv;
    }
  }
}

// ---------------- K2: attention, recompute-QK^T two-pass, QBLK=64 -----------
// swapped MFMA: mfma(K,Q) -> lane holds 4 consecutive k for one q-row.
// Pass A (col-split): QK^T -> exp2 -> masked UNNORMALIZED P: row sums + PV
// through DOUBLE-BUFFERED xor-swizzled LDS Pb: ONE lgkmcnt-only barrier per
// k-tile (barrier[i] orders write[i+1] into buf^1 against read[i-1] of buf^1).
// ctx = cacc * rowinv. Pass B (streaming, ZERO barriers, zero LDS): recompute
// scores, NT-write normalized attn; stores pipeline freely, never drained.
__global__ __launch_bounds__(256) void attn_kernel(
  const short* __restrict__ Qh, const short* __restrict__ Kh,
  const short* __restrict__ Vt, const unsigned* __restrict__ bits,
  float* __restrict__ attn, short* __restrict__ ctx)
{
  const int work = ((blockIdx.x & 7) << 8) | (blockIdx.x >> 3);  // 2048%8==0
  const int bh = work >> 4;
  const int q0 = (work & 15) * 64;
  const int b = bh >> 3, h = bh & 7;
  __shared__ unsigned mb[64*33];                  // mask bits, stride 33 words
  __shared__ __align__(16) short Pb[2][64*128];   // P tile, xor-swizzled, dbuf
  __shared__ float red[256];
  __shared__ float rowinv[64];
  const int tid = threadIdx.x, lane = tid & 63, wave = tid >> 6;
  const int col = lane & 15, kg = lane >> 4;
  const short* Qb = Qh + (size_t)bh*65536;
  const short* Kb = Kh + (size_t)bh*65536;
  const short* Vb = Vt + (size_t)bh*65536;
  const f4v zf = (f4v){0.f,0.f,0.f,0.f};

  { // stage this block's mask bits (64 rows x 32 words) into LDS
    const int r = tid >> 2, w = (tid & 3)*8;
    const unsigned* src = bits + (size_t)(b*1024 + q0 + r)*32 + w;
    uint4 w0 = *(const uint4*)src;
    uint4 w1 = *(const uint4*)(src + 4);
    unsigned* dst = &mb[r*33 + w];
    dst[0]=w0.x; dst[1]=w0.y; dst[2]=w0.z; dst[3]=w0.w;
    dst[4]=w1.x; dst[5]=w1.y; dst[6]=w1.z; dst[7]=w1.w;
  }

  // Q fragments (B-operand): rows q0..q0+63
  s8v qf[4][2];
  #pragma unroll
  for (int qi = 0; qi < 4; ++qi)
    #pragma unroll
    for (int ks = 0; ks < 2; ++ks)
      qf[qi][ks] = *(const s8v*)(Qb + (q0 + qi*16 + col)*64 + ks*32 + kg*8);

  __syncthreads();

  // ---- pass A: scores -> masked unnormalized P -> row sums + PV ----
  float sum[4] = {0.f, 0.f, 0.f, 0.f};
  f4v cacc[4] = {zf, zf, zf, zf};
  const int d0 = wave*16;
  const int sw = (col & 7) << 3;                  // Pb swizzle (shorts)
  for (int it = 0; it < 8; ++it){
    const int cur = it & 1;
    const int c0 = it*128 + wave*32;
    unsigned mw[4];
    #pragma unroll
    for (int qi = 0; qi < 4; ++qi) mw[qi] = mb[(qi*16 + col)*33 + (c0>>5)];
    #pragma unroll
    for (int ch = 0; ch < 2; ++ch){
      const int cc = c0 + ch*16;
      const short* kp = Kb + (cc + col)*64 + kg*8;
      s8v kf0 = *(const s8v*)kp;
      s8v kf1 = *(const s8v*)(kp + 32);
      #pragma unroll
      for (int qi = 0; qi < 4; ++qi){
        f4v a = mfma16(kf0, qf[qi][0], zf);
        a = mfma16(kf1, qf[qi][1], a);
        s4v pk;
        #pragma unroll
        for (int j = 0; j < 4; ++j){
          const int bit = ch*16 + kg*4 + j;
          float e = exp2f(a[j]);
          float p = ((mw[qi]>>bit)&1) ? 0.f : e;
          sum[qi] += p;
          pk[j] = f2bf(p);
        }
        // stage UNNORMALIZED P (bf16) for PV
        *(s4v*)&Pb[cur][(qi*16 + col)*128 + ((wave*32 + ch*16 + kg*4) ^ sw)] = pk;
      }
    }
    ldsbar();                     // Pb[cur] writes visible (LDS-only wait);
                                  // next iter writes Pb[cur^1] — no 2nd barrier
    #pragma unroll
    for (int sub = 0; sub < 4; ++sub){
      s8v vf = *(const s8v*)(Vb + (size_t)(d0 + col)*1024 + it*128 + sub*32 + kg*8);
      const int kr = (sub*32 + kg*8) ^ sw;
      #pragma unroll
      for (int qi = 0; qi < 4; ++qi){
        s8v pa = *(const s8v*)&Pb[cur][(qi*16 + col)*128 + kr];
        cacc[qi] = mfma16(pa, vf, cacc[qi]);
      }
    }
  }

  // reduce row sums -> rowinv
  #pragma unroll
  for (int qi = 0; qi < 4; ++qi){
    sum[qi] += __shfl_xor(sum[qi], 16);
    sum[qi] += __shfl_xor(sum[qi], 32);
  }
  if (kg == 0){
    #pragma unroll
    for (int qi = 0; qi < 4; ++qi) red[wave*64 + qi*16 + col] = sum[qi];
  }
  __syncthreads();
  if (tid < 64)
    rowinv[tid] = 1.0f / (red[tid] + red[64+tid] + red[128+tid] + red[192+tid]);
  __syncthreads();

  // ctx epilogue: normalize the unnormalized PV accumulator
  short* cb = ctx + (size_t)(b*1024 + q0)*512 + h*64 + d0 + col;
  #pragma unroll
  for (int qi = 0; qi < 4; ++qi)
    #pragma unroll
    for (int j = 0; j < 4; ++j)
      cb[(size_t)(qi*16 + kg*4 + j)*512] =
          f2bf(cacc[qi][j] * rowinv[qi*16 + kg*4 + j]);

  // ---- pass B: pure streaming normalized attn writes (no barriers/LDS) ----
  float inv[4];
  #pragma unroll
  for (int qi = 0; qi < 4; ++qi) inv[qi] = rowinv[qi*16 + col];
  float* ab = attn + (size_t)(bh*1024 + q0)*1024;
  for (int it = 0; it < 8; ++it){
    const int c0 = it*128 + wave*32;
    unsigned mw[4];
    #pragma unroll
    for (int qi = 0; qi < 4; ++qi) mw[qi] = mb[(qi*16 + col)*33 + (c0>>5)];
    #pragma unroll
    for (int ch = 0; ch < 2; ++ch){
      const int cc = c0 + ch*16;
      const short* kp = Kb + (cc + col)*64 + kg*8;
      s8v kf0 = *(const s8v*)kp;
      s8v kf1 = *(const s8v*)(kp + 32);
      #pragma unroll
      for (int qi = 0; qi < 4; ++qi){
        f4v a = mfma16(kf0, qf[qi][0], zf);
        a = mfma16(kf1, qf[qi][1], a);
        f4v p;
        #pragma unroll
        for (int j = 0; j < 4; ++j){
          const int bit = ch*16 + kg*4 + j;
          float e = exp2f(a[j]) * inv[qi];
          p[j] = ((mw[qi]>>bit)&1) ? 0.f : e;
        }
        __builtin_nontemporal_store(p,
            (f4v*)(ab + (size_t)(qi*16 + col)*1024 + cc + kg*4));
      }
    }
  }
}

// ---------------- K3: out-proj GEMM + residual + fused LayerNorm ------------
// 32 rows x 512 cols per block (full N -> LN block-local). grid 512. 4 waves,
// each wave owns a 128-col slice: acc[2 mfrag][8 nfrag]. Double-buffered LDS
// (1 ldsbar per k-step) + register prefetch.
__global__ __launch_bounds__(256) void outproj_ln_kernel(
  const short* __restrict__ ctx, const short* __restrict__ Wf,
  const float* __restrict__ resid, const float* __restrict__ gamma,
  const float* __restrict__ beta, float* __restrict__ out)
{
  const int m0 = blockIdx.x * 32;
  __shared__ __align__(16) short Alds[2][32*40];
  __shared__ float sred[32*4], qred[32*4];
  __shared__ float mLds[32], rLds[32];
  const int tid = threadIdx.x, lane = tid & 63, wave = tid >> 6;
  const int col = lane & 15, kg = lane >> 4;
  const int n0 = wave * 128;

  f4v acc[2][8];
  #pragma unroll
  for (int mf=0; mf<2; mf++)
    #pragma unroll
    for (int nf=0; nf<8; nf++) acc[mf][nf] = (f4v){0.f,0.f,0.f,0.f};

  const int arow = tid >> 3, ac = (tid & 7)*4;
  const short* Ap = ctx + (size_t)(m0 + arow)*512 + ac;

  s4v av = *(const s4v*)(Ap);
  int buf = 0;

  for (int k0 = 0; k0 < 512; k0 += 32){
    *(s4v*)&Alds[buf][arow*40 + ac] = av;
    if (k0 < 480) av = *(const s4v*)(Ap + k0 + 32);   // prefetch next
    ldsbar();                       // write visible; WAR covered by next barrier
    s8v af[2];
    #pragma unroll
    for (int mf=0; mf<2; mf++)
      af[mf] = *(const s8v*)&Alds[buf][(mf*16 + col)*40 + kg*8];
    #pragma unroll
    for (int nf=0; nf<8; nf++){
      s8v bf = *(const s8v*)(Wf + (size_t)(n0 + nf*16 + col)*512 + k0 + kg*8);
      #pragma unroll
      for (int mf=0; mf<2; mf++)
        acc[mf][nf] = mfma16(af[mf], bf, acc[mf][nf]);
    }
    buf ^= 1;
  }

  float g[8], bt[8];
  #pragma unroll
  for (int nf=0; nf<8; nf++){
    g[nf]  = gamma[n0 + nf*16 + col];
    bt[nf] = beta[n0 + nf*16 + col];
  }

  // residual add (in place) + per-row partial stats -> LDS reduce
  #pragma unroll
  for (int mf=0; mf<2; mf++)
    #pragma unroll
    for (int j=0; j<4; j++){
      const int rl = mf*16 + kg*4 + j;
      const size_t r = (size_t)(m0 + rl);
      float s = 0.f, qq = 0.f;
      #pragma unroll
      for (int nf=0; nf<8; nf++){
        float y = acc[mf][nf][j] + resid[r*512 + n0 + nf*16 + col];
        acc[mf][nf][j] = y;
        s += y; qq += y*y;
      }
      #pragma unroll
      for (int d=1; d<16; d<<=1){ s += __shfl_xor(s, d); qq += __shfl_xor(qq, d); }
      if (col == 0){ sred[rl*4 + wave] = s; qred[rl*4 + wave] = qq; }
    }
  __syncthreads();
  if (tid < 32){
    float S = sred[tid*4] + sred[tid*4+1] + sred[tid*4+2] + sred[tid*4+3];
    float Q = qred[tid*4] + qred[tid*4+1] + qred[tid*4+2] + qred[tid*4+3];
    float mean = S * (1.0f/512.0f);
    float var  = Q * (1.0f/512.0f) - mean*mean;
    mLds[tid] = mean;
    rLds[tid] = rsqrtf(var + 1e-6f);
  }
  __syncthreads();

  #pragma unroll
  for (int mf=0; mf<2; mf++)
    #pragma unroll
    for (int j=0; j<4; j++){
      const int rl = mf*16 + kg*4 + j;
      const size_t r = (size_t)(m0 + rl);
      const float mean = mLds[rl], rs = rLds[rl];
      #pragma unroll
      for (int nf=0; nf<8; nf++)
        out[r*512 + n0 + nf*16 + col] = (acc[mf][nf][j] - mean)*rs*g[nf] + bt[nf];
    }
}

extern "C" void kernel_launch(void* const* d_in, const int* in_sizes, int n_in,
                              void* d_out, int out_size, void* d_ws, size_t ws_size,
                              hipStream_t stream) {
  const float* q    = (const float*)d_in[0];
  const float* k    = (const float*)d_in[1];
  const float* v    = (const float*)d_in[2];
  const int*   mask = (const int*)d_in[3];
  const float* Wq   = (const float*)d_in[4];
  const float* Wk   = (const float*)d_in[5];
  const float* Wv   = (const float*)d_in[6];
  const float* Wfc  = (const float*)d_in[7];
  const float* gamma= (const float*)d_in[8];
  const float* beta = (const float*)d_in[9];

  char* ws = (char*)d_ws;
  short* Wt  = (short*)(ws);                       // 4*512*512 bf16 = 2 MB
  short* Qh  = (short*)(ws + ((size_t)2<<20));     // 16 MB
  short* Kh  = (short*)(ws + ((size_t)18<<20));    // 16 MB
  short* Vt  = (short*)(ws + ((size_t)34<<20));    // 16 MB
  short* ctx = (short*)(ws + ((size_t)50<<20));    // 16 MB

  float* out  = (float*)d_out;                     // [16384][512]
  float* attn = out + (size_t)16384*512;           // [128][1024][1024]
  // mask bitmask lives in d_out's `out` region (2 MB); consumed by attn_kernel,
  // then overwritten by outproj_ln_kernel (stream-ordered, so safe).
  unsigned* bits = (unsigned*)d_out;

  prep_kernel<<<dim3(2304,1,1), 256, 0, stream>>>(mask, bits, Wq, Wk, Wv, Wfc, Wt);
  proj_kernel <<<dim3(3072,1,1), 256, 0, stream>>>(q, k, v, Wt, Qh, Kh, Vt);
  attn_kernel <<<dim3(2048,1,1), 256, 0, stream>>>(Qh, Kh, Vt, bits, attn, ctx);
  outproj_ln_kernel<<<dim3(512,1,1), 256, 0, stream>>>(ctx, Wt + 3*262144, q,
                                                       gamma, beta, out);
}